// Round 10
// baseline (457.252 us; speedup 1.0000x reference)
//
#include <hip/hip_runtime.h>
#include <stdint.h>

#define C_DIM 8192
#define O_DIM 8192
#define M_DIM 256
#define NG    128     // C/64 groups total
#define NGH   64      // groups per k-half (k-split 2)
#define SUPS  8       // super-iterations per block (8 groups each)
#define RK    32

typedef float f32x4 __attribute__((ext_vector_type(4)));
typedef int   i32x4 __attribute__((ext_vector_type(4)));
typedef unsigned int u32;

__device__ __forceinline__ void gll16(const void* g, void* l) {
  __builtin_amdgcn_global_load_lds(
      (const __attribute__((address_space(1))) void*)g,
      (__attribute__((address_space(3))) void*)l, 16, 0, 0);
}
__device__ __forceinline__ int pack4(int a, int b, int c, int d) {
  return (a & 0xff) | ((b & 0xff) << 8) | ((c & 0xff) << 16) | (d << 24);
}

// ---------------------------------------------------------------------------
// k_lora: lact[m][r] = sum_k x[m][k] * pd[k][r]   (256 x 32, f32)
// ---------------------------------------------------------------------------
__global__ __launch_bounds__(256) void k_lora(const float* __restrict__ x,
                                              const float* __restrict__ pd,
                                              float* __restrict__ lact) {
  const int t  = threadIdx.x;
  const int rq = t & 7;
  const int kc = (t >> 3) & 15;
  const int ml = t >> 7;
  const int m  = blockIdx.x * 2 + ml;
  const float* xrow = x + (size_t)m * C_DIM + kc * 512;
  const float* pdp  = pd + (size_t)(kc * 512) * RK + rq * 4;
  float a0 = 0.f, a1 = 0.f, a2 = 0.f, a3 = 0.f;
  for (int k = 0; k < 512; k += 4) {
    float4 xv = *(const float4*)(xrow + k);
    float4 p0 = *(const float4*)(pdp + (size_t)(k + 0) * RK);
    float4 p1 = *(const float4*)(pdp + (size_t)(k + 1) * RK);
    float4 p2 = *(const float4*)(pdp + (size_t)(k + 2) * RK);
    float4 p3 = *(const float4*)(pdp + (size_t)(k + 3) * RK);
    a0 += xv.x * p0.x + xv.y * p1.x + xv.z * p2.x + xv.w * p3.x;
    a1 += xv.x * p0.y + xv.y * p1.y + xv.z * p2.y + xv.w * p3.y;
    a2 += xv.x * p0.z + xv.y * p1.z + xv.z * p2.z + xv.w * p3.z;
    a3 += xv.x * p0.w + xv.y * p1.w + xv.z * p2.w + xv.w * p3.w;
  }
  __shared__ float red[2][8][16][4];
  red[ml][rq][kc][0] = a0;
  red[ml][rq][kc][1] = a1;
  red[ml][rq][kc][2] = a2;
  red[ml][rq][kc][3] = a3;
  __syncthreads();
  if (t < 64) {
    const int ml2 = t >> 5, r = t & 31, rq2 = r >> 2, j = r & 3;
    float s = 0.f;
#pragma unroll
    for (int c = 0; c < 16; ++c) s += red[ml2][rq2][c][j];
    lact[(size_t)(blockIdx.x * 2 + ml2) * RK + r] = s;
  }
}

// ---------------------------------------------------------------------------
// k_prep: smooth + per-group int4 quantize.
//   scp[g*512 + m] = ascale ; scp[g*512 + 256 + m] = 8*(sum q)*ascale
//   wsA8[(MT*NG+g)*64+l] = 16 i8: q[m=MT*16+(l&15)][k=(l>>4)*16+j]
// ---------------------------------------------------------------------------
__global__ __launch_bounds__(256) void k_prep(const float* __restrict__ x,
                                              const float* __restrict__ smooth,
                                              float* __restrict__ scp,
                                              i32x4* __restrict__ wsA8) {
  const int t    = threadIdx.x;
  const int ml   = t & 15;
  const int gl   = t >> 4;
  const int MT   = blockIdx.x >> 3;
  const int gblk = blockIdx.x & 7;
  const int m = MT * 16 + ml;
  const int g = gblk * 16 + gl;
  const float* xp = x + (size_t)m * C_DIM + g * 64;
  const float* sp = smooth + g * 64;
  float xs[64];
  float amax = 0.0f;
#pragma unroll
  for (int i = 0; i < 64; i += 4) {
    float4 xv = *(const float4*)(xp + i);
    float4 sv = *(const float4*)(sp + i);
    xs[i + 0] = xv.x / sv.x;
    xs[i + 1] = xv.y / sv.y;
    xs[i + 2] = xv.z / sv.z;
    xs[i + 3] = xv.w / sv.w;
    amax = fmaxf(amax, fabsf(xs[i + 0]));
    amax = fmaxf(amax, fabsf(xs[i + 1]));
    amax = fmaxf(amax, fabsf(xs[i + 2]));
    amax = fmaxf(amax, fabsf(xs[i + 3]));
  }
  const float ascale = fmaxf(amax / 7.0f, 1e-8f);
  int qi[64];
  int rs = 0;
#pragma unroll
  for (int i = 0; i < 64; ++i) {
    float qv = fminf(fmaxf(rintf(xs[i] / ascale), -8.0f), 7.0f);
    qi[i] = (int)qv;
    rs += qi[i];
  }
  scp[(size_t)g * 512 + m]       = ascale;
  scp[(size_t)g * 512 + 256 + m] = 8.0f * (float)rs * ascale;
  const size_t base = ((size_t)(MT * NG + g)) * 64;
#pragma unroll
  for (int lg = 0; lg < 4; ++lg) {
    const int* q = qi + lg * 16;
    i32x4 c;
#pragma unroll
    for (int dw = 0; dw < 4; ++dw)
      c[dw] = pack4(q[dw * 4 + 0], q[dw * 4 + 1], q[dw * 4 + 2], q[dw * 4 + 3]);
    wsA8[base + lg * 16 + ml] = c;
  }
}

// ---------------------------------------------------------------------------
// k_main: K-split GEMM partials. 512 blocks x 512 thr (8 waves), 2/CU.
// Block: kh = bid&1 (4096 k = 64 groups), n0 = (bid>>1)*32, all 256 m.
// qweight read exactly once device-wide. Wave = 2 m-tiles x 2 n-tiles.
// Sup = 8 groups (2KB/row contiguous). B reg-staged (8x dwordx4) -> i8 pack
// -> padded-row LDS (528B stride); SC via gll16 dbuf (LINEAR 16B/lane dest —
// the R9 bug was a 32B/lane dest, which global_load_lds HW ignores);
// A depth-4 register ring. Counted vmcnt ledger: 16,16,16,16,6,6,6,6,end 8.
// Writes P[kh][m][n]; k_red reduces.
// ---------------------------------------------------------------------------
__global__ __launch_bounds__(512, 4) void k_main(
    const int* __restrict__ qw, const float* __restrict__ wsc,
    const float* __restrict__ scp, const i32x4* __restrict__ wsA8,
    float* __restrict__ P) {
  const int t    = threadIdx.x;
  const int bid  = blockIdx.x;
  const int kh   = bid & 1;
  const int n0   = (bid >> 1) * 32;
  const int g0   = kh * NGH;
  const int w    = t >> 6;
  const int l    = t & 63;
  const int lrow = l >> 4;
  const int lcol = l & 15;

  __shared__ char  ldsB[2][32 * 528];   // packed B, padded row stride 528
  __shared__ float ldsSC[2][4096];      // 8 groups x {as256, rs256}
  __shared__ float ldsW[NGH * 32];      // wscale table 8KB

  for (int i = t; i < NGH * 32; i += 512)
    ldsW[i] = wsc[(size_t)(g0 + (i >> 5)) * O_DIM + n0 + (i & 31)];

  // staging: thread t -> row sr (32), 32 contiguous k at sc*32
  const int sr = t >> 4, sc = t & 15;
  const int* gB = qw + (size_t)(n0 + sr) * C_DIM + kh * 4096 + sc * 32;
  const float* gSC = scp + (size_t)g0 * 512 + t * 4;   // 16B/lane linear
  const int wOff = sr * 528 + sc * 32;   // packed dst byte offset
  const i32x4* gA0 = wsA8 + ((size_t)(w * 2 + 0) * NG + g0) * 64 + l;
  const i32x4* gA1 = wsA8 + ((size_t)(w * 2 + 1) * NG + g0) * 64 + l;

  __syncthreads();   // ldsW ready; clean vm/lgkm ledger

  i32x4 br0, br1, br2, br3, br4, br5, br6, br7;
  i32x4 R0_0, R0_1, R1_0, R1_1, R2_0, R2_1, R3_0, R3_1;

#define LOADB(S)                                                               \
  br0 = *(const i32x4*)(gB + (S) * 512 + 0);                                   \
  br1 = *(const i32x4*)(gB + (S) * 512 + 4);                                   \
  br2 = *(const i32x4*)(gB + (S) * 512 + 8);                                   \
  br3 = *(const i32x4*)(gB + (S) * 512 + 12);                                  \
  br4 = *(const i32x4*)(gB + (S) * 512 + 16);                                  \
  br5 = *(const i32x4*)(gB + (S) * 512 + 20);                                  \
  br6 = *(const i32x4*)(gB + (S) * 512 + 24);                                  \
  br7 = *(const i32x4*)(gB + (S) * 512 + 28);
#define LOADSC(S, BUF)                                                         \
  gll16(gSC + (size_t)(S) * 4096, &ldsSC[BUF][t * 4]);                         \
  gll16(gSC + (size_t)(S) * 4096 + 2048, &ldsSC[BUF][2048 + t * 4]);
#define PACKW(BUF)                                                             \
  {                                                                            \
    i32x4 pk0, pk1;                                                            \
    pk0[0] = pack4(br0[0], br0[1], br0[2], br0[3]);                            \
    pk0[1] = pack4(br1[0], br1[1], br1[2], br1[3]);                            \
    pk0[2] = pack4(br2[0], br2[1], br2[2], br2[3]);                            \
    pk0[3] = pack4(br3[0], br3[1], br3[2], br3[3]);                            \
    pk1[0] = pack4(br4[0], br4[1], br4[2], br4[3]);                            \
    pk1[1] = pack4(br5[0], br5[1], br5[2], br5[3]);                            \
    pk1[2] = pack4(br6[0], br6[1], br6[2], br6[3]);                            \
    pk1[3] = pack4(br7[0], br7[1], br7[2], br7[3]);                            \
    *(i32x4*)&ldsB[BUF][wOff] = pk0;                                           \
    *(i32x4*)&ldsB[BUF][wOff + 16] = pk1;                                      \
  }

  // prologue: stage sup0 (10 vm) + A groups 0..3 (8 vm) = 18 outstanding
  LOADB(0)
  LOADSC(0, 0)
  R0_0 = gA0[0 * 64];  R0_1 = gA1[0 * 64];
  R1_0 = gA0[1 * 64];  R1_1 = gA1[1 * 64];
  R2_0 = gA0[2 * 64];  R2_1 = gA1[2 * 64];
  R3_0 = gA0[3 * 64];  R3_1 = gA1[3 * 64];
  asm volatile("s_waitcnt vmcnt(8)" ::: "memory");   // retire staging batch
  PACKW(0)
  asm volatile("s_waitcnt lgkmcnt(0)" ::: "memory");
  __builtin_amdgcn_s_barrier();

  f32x4 acc00 = (f32x4){0.f, 0.f, 0.f, 0.f};
  f32x4 acc01 = (f32x4){0.f, 0.f, 0.f, 0.f};
  f32x4 acc10 = (f32x4){0.f, 0.f, 0.f, 0.f};
  f32x4 acc11 = (f32x4){0.f, 0.f, 0.f, 0.f};
  const i32x4 z = (i32x4){0, 0, 0, 0};

#define SUBJ(J, RA0, RA1, VMC)                                                 \
  {                                                                            \
    asm volatile("s_waitcnt vmcnt(" #VMC ")" ::: "memory");                    \
    const char* bb = &ldsB[s & 1][0];                                          \
    i32x4 bf0 = *(const i32x4*)(bb + lcol * 528 + (J) * 64 + lrow * 16);       \
    i32x4 bf1 = *(const i32x4*)(bb + (16 + lcol) * 528 + (J) * 64 + lrow * 16);\
    const float* scb = &ldsSC[s & 1][(J) * 512];                               \
    f32x4 as0 = *(const f32x4*)(scb + (w * 2 + 0) * 16 + lrow * 4);            \
    f32x4 rs0 = *(const f32x4*)(scb + 256 + (w * 2 + 0) * 16 + lrow * 4);      \
    f32x4 as1 = *(const f32x4*)(scb + (w * 2 + 1) * 16 + lrow * 4);            \
    f32x4 rs1 = *(const f32x4*)(scb + 256 + (w * 2 + 1) * 16 + lrow * 4);      \
    const float wsv0 = ldsW[(s * 8 + (J)) * 32 + lcol];                        \
    const float wsv1 = ldsW[(s * 8 + (J)) * 32 + 16 + lcol];                   \
    i32x4 d00 = __builtin_amdgcn_mfma_i32_16x16x64_i8(RA0, bf0, z, 0, 0, 0);   \
    i32x4 d01 = __builtin_amdgcn_mfma_i32_16x16x64_i8(RA0, bf1, z, 0, 0, 0);   \
    i32x4 d10 = __builtin_amdgcn_mfma_i32_16x16x64_i8(RA1, bf0, z, 0, 0, 0);   \
    i32x4 d11 = __builtin_amdgcn_mfma_i32_16x16x64_i8(RA1, bf1, z, 0, 0, 0);   \
    {                                                                          \
      int lgn = s * 8 + (J) + 4;                                               \
      if (lgn > NGH - 1) lgn = NGH - 1;                                        \
      RA0 = gA0[(size_t)lgn * 64];                                             \
      RA1 = gA1[(size_t)lgn * 64];                                             \
    }                                                                          \
    f32x4 df;                                                                  \
    df[0] = (float)d00[0]; df[1] = (float)d00[1];                              \
    df[2] = (float)d00[2]; df[3] = (float)d00[3];                              \
    acc00 += wsv0 * (as0 * df - rs0);                                          \
    df[0] = (float)d01[0]; df[1] = (float)d01[1];                              \
    df[2] = (float)d01[2]; df[3] = (float)d01[3];                              \
    acc01 += wsv1 * (as0 * df - rs0);                                          \
    df[0] = (float)d10[0]; df[1] = (float)d10[1];                              \
    df[2] = (float)d10[2]; df[3] = (float)d10[3];                              \
    acc10 += wsv0 * (as1 * df - rs1);                                          \
    df[0] = (float)d11[0]; df[1] = (float)d11[1];                              \
    df[2] = (float)d11[2]; df[3] = (float)d11[3];                              \
    acc11 += wsv1 * (as1 * df - rs1);                                          \
  }

  for (int s = 0; s < SUPS; ++s) {
    // stage sup s+1 (10 vm-ops; s=7 stages a harmless duplicate)
    const int sn = (s < SUPS - 1) ? s + 1 : SUPS - 1;
    const int nb = (s + 1) & 1;
    LOADB(sn)
    LOADSC(sn, nb)
    SUBJ(0, R0_0, R0_1, 16)
    SUBJ(1, R1_0, R1_1, 16)
    SUBJ(2, R2_0, R2_1, 16)
    SUBJ(3, R3_0, R3_1, 16)
    SUBJ(4, R0_0, R0_1, 6)
    SUBJ(5, R1_0, R1_1, 6)
    SUBJ(6, R2_0, R2_1, 6)
    SUBJ(7, R3_0, R3_1, 6)
    asm volatile("s_waitcnt vmcnt(8)" ::: "memory");   // safety: staging done
    PACKW(nb)
    asm volatile("s_waitcnt lgkmcnt(0)" ::: "memory");
    __builtin_amdgcn_s_barrier();
  }
#undef SUBJ
#undef LOADB
#undef LOADSC
#undef PACKW

  // write partials
  float* Pk = P + (size_t)kh * (M_DIM * O_DIM);
#pragma unroll
  for (int mi = 0; mi < 2; ++mi) {
#pragma unroll
    for (int ni = 0; ni < 2; ++ni) {
      const f32x4 av = (mi == 0) ? (ni == 0 ? acc00 : acc01)
                                 : (ni == 0 ? acc10 : acc11);
      const int n = n0 + ni * 16 + lcol;
#pragma unroll
      for (int j = 0; j < 4; ++j) {
        const int m = (w * 2 + mi) * 16 + lrow * 4 + j;
        Pk[(size_t)m * O_DIM + n] = av[j];
      }
    }
  }
}

// ---------------------------------------------------------------------------
// k_red: out = P0 + P1 + bias + lact . pu^T   (256 blocks x 256 thr)
// ---------------------------------------------------------------------------
__global__ __launch_bounds__(256) void k_red(const float* __restrict__ P,
                                             const float* __restrict__ lact,
                                             const float* __restrict__ pu,
                                             const float* __restrict__ bias,
                                             float* __restrict__ out) {
  const int t  = threadIdx.x;
  const int tn = t & 31;
  const int tm = t >> 5;
  const int n0 = blockIdx.x * 32;
  __shared__ float puL[32][33];   // +1 pad: bank-spread
  for (int i = t; i < 1024; i += 256)
    puL[i >> 5][i & 31] = pu[(size_t)(n0 + (i >> 5)) * RK + (i & 31)];
  __syncthreads();
  const int n = n0 + tn;
  const float bv = bias[n];
  for (int m = tm; m < M_DIM; m += 8) {
    const float* lp = lact + (size_t)m * RK;
    float s = bv;
#pragma unroll
    for (int r = 0; r < 32; r += 4) {
      float4 lv = *(const float4*)(lp + r);
      s += lv.x * puL[tn][r] + lv.y * puL[tn][r + 1] + lv.z * puL[tn][r + 2] +
           lv.w * puL[tn][r + 3];
    }
    const size_t o = (size_t)m * O_DIM + n;
    out[o] = P[o] + P[(size_t)M_DIM * O_DIM + o] + s;
  }
}

// ---------------------------------------------------------------------------
extern "C" void kernel_launch(void* const* d_in, const int* in_sizes, int n_in,
                              void* d_out, int out_size, void* d_ws,
                              size_t ws_size, hipStream_t stream) {
  const float* x      = (const float*)d_in[0];
  const int*   qw     = (const int*)d_in[1];
  const float* wsc    = (const float*)d_in[2];
  const float* smooth = (const float*)d_in[3];
  const float* pd     = (const float*)d_in[4];
  const float* pu     = (const float*)d_in[5];
  const float* bias   = (const float*)d_in[6];
  float* out = (float*)d_out;

  char* ws = (char*)d_ws;
  float* lact = (float*)ws;                      // 32 KB
  float* scp  = (float*)(ws + 32 * 1024);        // 256 KB
  i32x4* wsA8 = (i32x4*)(ws + 288 * 1024);       // 2 MB
  float* P    = (float*)(ws + 2336 * 1024);      // 2 x 8 MB partials

  hipLaunchKernelGGL(k_prep, dim3(128), dim3(256), 0, stream, x, smooth, scp,
                     wsA8);
  hipLaunchKernelGGL(k_lora, dim3(128), dim3(256), 0, stream, x, pd, lact);
  hipLaunchKernelGGL(k_main, dim3(512), dim3(512), 0, stream, qw, wsc, scp,
                     wsA8, P);
  hipLaunchKernelGGL(k_red, dim3(256), dim3(256), 0, stream, P, lact, pu, bias,
                     out);
}

// Round 11
// 192.735 us; speedup vs baseline: 2.3724x; 2.3724x over previous
//
#include <hip/hip_runtime.h>
#include <stdint.h>

#define C_DIM 8192
#define O_DIM 8192
#define M_DIM 256
#define NG    128     // C/64 groups total
#define NGH   64      // groups per k-half (k-split 2)
#define SUPS  8       // super-iterations per block (8 groups each)
#define RK    32

typedef float f32x4 __attribute__((ext_vector_type(4)));
typedef int   i32x4 __attribute__((ext_vector_type(4)));
typedef unsigned int u32;

__device__ __forceinline__ void gll16(const void* g, void* l) {
  __builtin_amdgcn_global_load_lds(
      (const __attribute__((address_space(1))) void*)g,
      (__attribute__((address_space(3))) void*)l, 16, 0, 0);
}
__device__ __forceinline__ int pack4(int a, int b, int c, int d) {
  return (a & 0xff) | ((b & 0xff) << 8) | ((c & 0xff) << 16) | (d << 24);
}

// ---------------------------------------------------------------------------
// k_lora: lact[m][r] = sum_k x[m][k] * pd[k][r]   (256 x 32, f32)
// ---------------------------------------------------------------------------
__global__ __launch_bounds__(256) void k_lora(const float* __restrict__ x,
                                              const float* __restrict__ pd,
                                              float* __restrict__ lact) {
  const int t  = threadIdx.x;
  const int rq = t & 7;
  const int kc = (t >> 3) & 15;
  const int ml = t >> 7;
  const int m  = blockIdx.x * 2 + ml;
  const float* xrow = x + (size_t)m * C_DIM + kc * 512;
  const float* pdp  = pd + (size_t)(kc * 512) * RK + rq * 4;
  float a0 = 0.f, a1 = 0.f, a2 = 0.f, a3 = 0.f;
  for (int k = 0; k < 512; k += 4) {
    float4 xv = *(const float4*)(xrow + k);
    float4 p0 = *(const float4*)(pdp + (size_t)(k + 0) * RK);
    float4 p1 = *(const float4*)(pdp + (size_t)(k + 1) * RK);
    float4 p2 = *(const float4*)(pdp + (size_t)(k + 2) * RK);
    float4 p3 = *(const float4*)(pdp + (size_t)(k + 3) * RK);
    a0 += xv.x * p0.x + xv.y * p1.x + xv.z * p2.x + xv.w * p3.x;
    a1 += xv.x * p0.y + xv.y * p1.y + xv.z * p2.y + xv.w * p3.y;
    a2 += xv.x * p0.z + xv.y * p1.z + xv.z * p2.z + xv.w * p3.z;
    a3 += xv.x * p0.w + xv.y * p1.w + xv.z * p2.w + xv.w * p3.w;
  }
  __shared__ float red[2][8][16][4];
  red[ml][rq][kc][0] = a0;
  red[ml][rq][kc][1] = a1;
  red[ml][rq][kc][2] = a2;
  red[ml][rq][kc][3] = a3;
  __syncthreads();
  if (t < 64) {
    const int ml2 = t >> 5, r = t & 31, rq2 = r >> 2, j = r & 3;
    float s = 0.f;
#pragma unroll
    for (int c = 0; c < 16; ++c) s += red[ml2][rq2][c][j];
    lact[(size_t)(blockIdx.x * 2 + ml2) * RK + r] = s;
  }
}

// ---------------------------------------------------------------------------
// k_prep: smooth + per-group int4 quantize.
//   scp[g*512 + m] = ascale ; scp[g*512 + 256 + m] = 8*(sum q)*ascale
//   wsA8[(MT*NG+g)*64+l] = 16 i8: q[m=MT*16+(l&15)][k=(l>>4)*16+j]
// ---------------------------------------------------------------------------
__global__ __launch_bounds__(256) void k_prep(const float* __restrict__ x,
                                              const float* __restrict__ smooth,
                                              float* __restrict__ scp,
                                              i32x4* __restrict__ wsA8) {
  const int t    = threadIdx.x;
  const int ml   = t & 15;
  const int gl   = t >> 4;
  const int MT   = blockIdx.x >> 3;
  const int gblk = blockIdx.x & 7;
  const int m = MT * 16 + ml;
  const int g = gblk * 16 + gl;
  const float* xp = x + (size_t)m * C_DIM + g * 64;
  const float* sp = smooth + g * 64;
  float xs[64];
  float amax = 0.0f;
#pragma unroll
  for (int i = 0; i < 64; i += 4) {
    float4 xv = *(const float4*)(xp + i);
    float4 sv = *(const float4*)(sp + i);
    xs[i + 0] = xv.x / sv.x;
    xs[i + 1] = xv.y / sv.y;
    xs[i + 2] = xv.z / sv.z;
    xs[i + 3] = xv.w / sv.w;
    amax = fmaxf(amax, fabsf(xs[i + 0]));
    amax = fmaxf(amax, fabsf(xs[i + 1]));
    amax = fmaxf(amax, fabsf(xs[i + 2]));
    amax = fmaxf(amax, fabsf(xs[i + 3]));
  }
  const float ascale = fmaxf(amax / 7.0f, 1e-8f);
  int qi[64];
  int rs = 0;
#pragma unroll
  for (int i = 0; i < 64; ++i) {
    float qv = fminf(fmaxf(rintf(xs[i] / ascale), -8.0f), 7.0f);
    qi[i] = (int)qv;
    rs += qi[i];
  }
  scp[(size_t)g * 512 + m]       = ascale;
  scp[(size_t)g * 512 + 256 + m] = 8.0f * (float)rs * ascale;
  const size_t base = ((size_t)(MT * NG + g)) * 64;
#pragma unroll
  for (int lg = 0; lg < 4; ++lg) {
    const int* q = qi + lg * 16;
    i32x4 c;
#pragma unroll
    for (int dw = 0; dw < 4; ++dw)
      c[dw] = pack4(q[dw * 4 + 0], q[dw * 4 + 1], q[dw * 4 + 2], q[dw * 4 + 3]);
    wsA8[base + lg * 16 + ml] = c;
  }
}

// ---------------------------------------------------------------------------
// k_main: K-split GEMM partials. 512 blocks x 512 thr (8 waves).
// __launch_bounds__(512, 2): 128-VGPR tier -> state (~115 VGPR) fits with
// ZERO SPILLS (the R4/R8/R10 poison was (512,4) -> 64-VGPR cap -> 385 MB
// scratch traffic). 2 blocks/CU, 16 waves/CU.
// Block: kh = bid&1 (4096 k = 64 groups), n0 = (bid>>1)*32, all 256 m.
// qweight read exactly once device-wide, 2KB/row contiguous per sup.
// B reg-staged (8x dwordx4) -> i8 pack -> padded-row LDS (528B stride);
// SC via gll16 dbuf (linear 16B/lane dest); A depth-4 register ring.
// Counted vmcnt ledger: 16,16,16,16,6,6,6,6, end 8. Writes P[kh][m][n].
// ---------------------------------------------------------------------------
__global__ __launch_bounds__(512, 2) void k_main(
    const int* __restrict__ qw, const float* __restrict__ wsc,
    const float* __restrict__ scp, const i32x4* __restrict__ wsA8,
    float* __restrict__ P) {
  const int t    = threadIdx.x;
  const int bid  = blockIdx.x;
  const int kh   = bid & 1;
  const int n0   = (bid >> 1) * 32;
  const int g0   = kh * NGH;
  const int w    = t >> 6;
  const int l    = t & 63;
  const int lrow = l >> 4;
  const int lcol = l & 15;

  __shared__ char  ldsB[2][32 * 528];   // packed B, padded row stride 528
  __shared__ float ldsSC[2][4096];      // 8 groups x {as256, rs256}
  __shared__ float ldsW[NGH * 32];      // wscale table 8KB

  for (int i = t; i < NGH * 32; i += 512)
    ldsW[i] = wsc[(size_t)(g0 + (i >> 5)) * O_DIM + n0 + (i & 31)];

  // staging: thread t -> row sr (32), 32 contiguous k at sc*32
  const int sr = t >> 4, sc = t & 15;
  const int* gB = qw + (size_t)(n0 + sr) * C_DIM + kh * 4096 + sc * 32;
  const float* gSC = scp + (size_t)g0 * 512 + t * 4;   // 16B/lane linear
  const int wOff = sr * 528 + sc * 32;   // packed dst byte offset
  const i32x4* gA0 = wsA8 + ((size_t)(w * 2 + 0) * NG + g0) * 64 + l;
  const i32x4* gA1 = wsA8 + ((size_t)(w * 2 + 1) * NG + g0) * 64 + l;

  __syncthreads();   // ldsW ready; clean vm/lgkm ledger

  i32x4 br0, br1, br2, br3, br4, br5, br6, br7;
  i32x4 R0_0, R0_1, R1_0, R1_1, R2_0, R2_1, R3_0, R3_1;

#define LOADB(S)                                                               \
  br0 = *(const i32x4*)(gB + (S) * 512 + 0);                                   \
  br1 = *(const i32x4*)(gB + (S) * 512 + 4);                                   \
  br2 = *(const i32x4*)(gB + (S) * 512 + 8);                                   \
  br3 = *(const i32x4*)(gB + (S) * 512 + 12);                                  \
  br4 = *(const i32x4*)(gB + (S) * 512 + 16);                                  \
  br5 = *(const i32x4*)(gB + (S) * 512 + 20);                                  \
  br6 = *(const i32x4*)(gB + (S) * 512 + 24);                                  \
  br7 = *(const i32x4*)(gB + (S) * 512 + 28);
#define LOADSC(S, BUF)                                                         \
  gll16(gSC + (size_t)(S) * 4096, &ldsSC[BUF][t * 4]);                         \
  gll16(gSC + (size_t)(S) * 4096 + 2048, &ldsSC[BUF][2048 + t * 4]);
#define PACKW(BUF)                                                             \
  {                                                                            \
    i32x4 pk0, pk1;                                                            \
    pk0[0] = pack4(br0[0], br0[1], br0[2], br0[3]);                            \
    pk0[1] = pack4(br1[0], br1[1], br1[2], br1[3]);                            \
    pk0[2] = pack4(br2[0], br2[1], br2[2], br2[3]);                            \
    pk0[3] = pack4(br3[0], br3[1], br3[2], br3[3]);                            \
    pk1[0] = pack4(br4[0], br4[1], br4[2], br4[3]);                            \
    pk1[1] = pack4(br5[0], br5[1], br5[2], br5[3]);                            \
    pk1[2] = pack4(br6[0], br6[1], br6[2], br6[3]);                            \
    pk1[3] = pack4(br7[0], br7[1], br7[2], br7[3]);                            \
    *(i32x4*)&ldsB[BUF][wOff] = pk0;                                           \
    *(i32x4*)&ldsB[BUF][wOff + 16] = pk1;                                      \
  }

  // prologue: stage sup0 (10 vm) + A groups 0..3 (8 vm) = 18 outstanding
  LOADB(0)
  LOADSC(0, 0)
  R0_0 = gA0[0 * 64];  R0_1 = gA1[0 * 64];
  R1_0 = gA0[1 * 64];  R1_1 = gA1[1 * 64];
  R2_0 = gA0[2 * 64];  R2_1 = gA1[2 * 64];
  R3_0 = gA0[3 * 64];  R3_1 = gA1[3 * 64];
  asm volatile("s_waitcnt vmcnt(8)" ::: "memory");   // retire staging batch
  PACKW(0)
  asm volatile("s_waitcnt lgkmcnt(0)" ::: "memory");
  __builtin_amdgcn_s_barrier();

  f32x4 acc00 = (f32x4){0.f, 0.f, 0.f, 0.f};
  f32x4 acc01 = (f32x4){0.f, 0.f, 0.f, 0.f};
  f32x4 acc10 = (f32x4){0.f, 0.f, 0.f, 0.f};
  f32x4 acc11 = (f32x4){0.f, 0.f, 0.f, 0.f};
  const i32x4 z = (i32x4){0, 0, 0, 0};

#define SUBJ(J, RA0, RA1, VMC)                                                 \
  {                                                                            \
    asm volatile("s_waitcnt vmcnt(" #VMC ")" ::: "memory");                    \
    const char* bb = &ldsB[s & 1][0];                                          \
    i32x4 bf0 = *(const i32x4*)(bb + lcol * 528 + (J) * 64 + lrow * 16);       \
    i32x4 bf1 = *(const i32x4*)(bb + (16 + lcol) * 528 + (J) * 64 + lrow * 16);\
    const float* scb = &ldsSC[s & 1][(J) * 512];                               \
    f32x4 as0 = *(const f32x4*)(scb + (w * 2 + 0) * 16 + lrow * 4);            \
    f32x4 rs0 = *(const f32x4*)(scb + 256 + (w * 2 + 0) * 16 + lrow * 4);      \
    f32x4 as1 = *(const f32x4*)(scb + (w * 2 + 1) * 16 + lrow * 4);            \
    f32x4 rs1 = *(const f32x4*)(scb + 256 + (w * 2 + 1) * 16 + lrow * 4);      \
    const float wsv0 = ldsW[(s * 8 + (J)) * 32 + lcol];                        \
    const float wsv1 = ldsW[(s * 8 + (J)) * 32 + 16 + lcol];                   \
    i32x4 d00 = __builtin_amdgcn_mfma_i32_16x16x64_i8(RA0, bf0, z, 0, 0, 0);   \
    i32x4 d01 = __builtin_amdgcn_mfma_i32_16x16x64_i8(RA0, bf1, z, 0, 0, 0);   \
    i32x4 d10 = __builtin_amdgcn_mfma_i32_16x16x64_i8(RA1, bf0, z, 0, 0, 0);   \
    i32x4 d11 = __builtin_amdgcn_mfma_i32_16x16x64_i8(RA1, bf1, z, 0, 0, 0);   \
    {                                                                          \
      int lgn = s * 8 + (J) + 4;                                               \
      if (lgn > NGH - 1) lgn = NGH - 1;                                        \
      RA0 = gA0[(size_t)lgn * 64];                                             \
      RA1 = gA1[(size_t)lgn * 64];                                             \
    }                                                                          \
    f32x4 df;                                                                  \
    df[0] = (float)d00[0]; df[1] = (float)d00[1];                              \
    df[2] = (float)d00[2]; df[3] = (float)d00[3];                              \
    acc00 += wsv0 * (as0 * df - rs0);                                          \
    df[0] = (float)d01[0]; df[1] = (float)d01[1];                              \
    df[2] = (float)d01[2]; df[3] = (float)d01[3];                              \
    acc01 += wsv1 * (as0 * df - rs0);                                          \
    df[0] = (float)d10[0]; df[1] = (float)d10[1];                              \
    df[2] = (float)d10[2]; df[3] = (float)d10[3];                              \
    acc10 += wsv0 * (as1 * df - rs1);                                          \
    df[0] = (float)d11[0]; df[1] = (float)d11[1];                              \
    df[2] = (float)d11[2]; df[3] = (float)d11[3];                              \
    acc11 += wsv1 * (as1 * df - rs1);                                          \
  }

  for (int s = 0; s < SUPS; ++s) {
    // stage sup s+1 (10 vm-ops; s=7 stages a harmless duplicate)
    const int sn = (s < SUPS - 1) ? s + 1 : SUPS - 1;
    const int nb = (s + 1) & 1;
    LOADB(sn)
    LOADSC(sn, nb)
    SUBJ(0, R0_0, R0_1, 16)
    SUBJ(1, R1_0, R1_1, 16)
    SUBJ(2, R2_0, R2_1, 16)
    SUBJ(3, R3_0, R3_1, 16)
    SUBJ(4, R0_0, R0_1, 6)
    SUBJ(5, R1_0, R1_1, 6)
    SUBJ(6, R2_0, R2_1, 6)
    SUBJ(7, R3_0, R3_1, 6)
    asm volatile("s_waitcnt vmcnt(8)" ::: "memory");   // safety: staging done
    PACKW(nb)
    asm volatile("s_waitcnt lgkmcnt(0)" ::: "memory");
    __builtin_amdgcn_s_barrier();
  }
#undef SUBJ
#undef LOADB
#undef LOADSC
#undef PACKW

  // write partials
  float* Pk = P + (size_t)kh * (M_DIM * O_DIM);
#pragma unroll
  for (int mi = 0; mi < 2; ++mi) {
#pragma unroll
    for (int ni = 0; ni < 2; ++ni) {
      const f32x4 av = (mi == 0) ? (ni == 0 ? acc00 : acc01)
                                 : (ni == 0 ? acc10 : acc11);
      const int n = n0 + ni * 16 + lcol;
#pragma unroll
      for (int j = 0; j < 4; ++j) {
        const int m = (w * 2 + mi) * 16 + lrow * 4 + j;
        Pk[(size_t)m * O_DIM + n] = av[j];
      }
    }
  }
}

// ---------------------------------------------------------------------------
// k_red: out = P0 + P1 + bias + lact . pu^T   (256 blocks x 256 thr)
// ---------------------------------------------------------------------------
__global__ __launch_bounds__(256) void k_red(const float* __restrict__ P,
                                             const float* __restrict__ lact,
                                             const float* __restrict__ pu,
                                             const float* __restrict__ bias,
                                             float* __restrict__ out) {
  const int t  = threadIdx.x;
  const int tn = t & 31;
  const int tm = t >> 5;
  const int n0 = blockIdx.x * 32;
  __shared__ float puL[32][33];   // +1 pad: bank-spread
  for (int i = t; i < 1024; i += 256)
    puL[i >> 5][i & 31] = pu[(size_t)(n0 + (i >> 5)) * RK + (i & 31)];
  __syncthreads();
  const int n = n0 + tn;
  const float bv = bias[n];
  for (int m = tm; m < M_DIM; m += 8) {
    const float* lp = lact + (size_t)m * RK;
    float s = bv;
#pragma unroll
    for (int r = 0; r < 32; r += 4) {
      float4 lv = *(const float4*)(lp + r);
      s += lv.x * puL[tn][r] + lv.y * puL[tn][r + 1] + lv.z * puL[tn][r + 2] +
           lv.w * puL[tn][r + 3];
    }
    const size_t o = (size_t)m * O_DIM + n;
    out[o] = P[o] + P[(size_t)M_DIM * O_DIM + o] + s;
  }
}

// ---------------------------------------------------------------------------
extern "C" void kernel_launch(void* const* d_in, const int* in_sizes, int n_in,
                              void* d_out, int out_size, void* d_ws,
                              size_t ws_size, hipStream_t stream) {
  const float* x      = (const float*)d_in[0];
  const int*   qw     = (const int*)d_in[1];
  const float* wsc    = (const float*)d_in[2];
  const float* smooth = (const float*)d_in[3];
  const float* pd     = (const float*)d_in[4];
  const float* pu     = (const float*)d_in[5];
  const float* bias   = (const float*)d_in[6];
  float* out = (float*)d_out;

  char* ws = (char*)d_ws;
  float* lact = (float*)ws;                      // 32 KB
  float* scp  = (float*)(ws + 32 * 1024);        // 256 KB
  i32x4* wsA8 = (i32x4*)(ws + 288 * 1024);       // 2 MB
  float* P    = (float*)(ws + 2336 * 1024);      // 2 x 8 MB partials

  hipLaunchKernelGGL(k_prep, dim3(128), dim3(256), 0, stream, x, smooth, scp,
                     wsA8);
  hipLaunchKernelGGL(k_lora, dim3(128), dim3(256), 0, stream, x, pd, lact);
  hipLaunchKernelGGL(k_main, dim3(512), dim3(512), 0, stream, qw, wsc, scp,
                     wsA8, P);
  hipLaunchKernelGGL(k_red, dim3(256), dim3(256), 0, stream, P, lact, pu, bias,
                     out);
}